// Round 11
// baseline (296.179 us; speedup 1.0000x reference)
//
#include <hip/hip_runtime.h>
#include <math.h>
#include <float.h>

#define PH 7
#define RLEN 32   // ints per roi in workspace

// ---- exact integer emulation of the reference's fast-math f32 binning ----
// bin = RN_f32(roi * RN_f32(1/7));  RN_f32(1/7) = 9586981 * 2^-26
#define C7 9586981LL

__device__ __forceinline__ long long round24(long long v) {
    if (v == 0) return 0;
    int L = 64 - __clzll((unsigned long long)v);
    int sh = L - 24;
    if (sh <= 0) return v;
    long long rem  = v & ((1LL << sh) - 1);
    long long base = v >> sh;
    long long half = 1LL << (sh - 1);
    if (rem > half || (rem == half && (base & 1))) base++;
    return base << sh;
}
__device__ __forceinline__ long long bin_q26(int roi) {
    return round24((long long)roi * C7);
}
__device__ __forceinline__ int floor_k(long long b26, int k) {
    long long v = round24((long long)k * b26);
    return (int)(v >> 26);
}
__device__ __forceinline__ int ceil_k(long long b26, int k) {
    long long v = round24((long long)k * b26);
    return (int)((v + ((1LL << 26) - 1)) >> 26);
}

// Per-ROI bounds (ints): [0]=b, [1..7]=hstart, [8..14]=hend,
// [15] = qs | qe<<8 (window column-quad range), [16..22]=ws, [23..29]=we
__global__ void roi_bounds_kernel(const float* __restrict__ rois,
                                  int* __restrict__ wsbuf, int R) {
    int r = blockIdx.x * blockDim.x + threadIdx.x;
    if (r >= R) return;
    const int H = 64, W = 64;
    const float* roi = rois + r * 5;
    int b  = (int)roi[0];
    int x1 = (int)rintf(roi[1] * 0.0625f);
    int y1 = (int)rintf(roi[2] * 0.0625f);
    int x2 = (int)rintf(roi[3] * 0.0625f);
    int y2 = (int)rintf(roi[4] * 0.0625f);

    int roi_w = max(x2 - x1 + 1, 1);
    int roi_h = max(y2 - y1 + 1, 1);
    long long bh = bin_q26(roi_h);
    long long bw = bin_q26(roi_w);

    int* o = wsbuf + r * RLEN;
    o[0] = b;
    int ws0 = 64, we6 = 0;
    #pragma unroll
    for (int i = 0; i < PH; ++i) {
        int hs = min(max(y1 + floor_k(bh, i),     0), H);
        int he = min(max(y1 + ceil_k (bh, i + 1), 0), H);
        int wst = min(max(x1 + floor_k(bw, i),     0), W);
        int wen = min(max(x1 + ceil_k (bw, i + 1), 0), W);
        o[1 + i]  = hs;
        o[8 + i]  = he;
        o[16 + i] = wst;
        o[23 + i] = wen;
        if (i == 0) ws0 = wst;
        if (i == 6) we6 = wen;
    }
    int qs = ws0 >> 2;
    int qe = (we6 + 3) >> 2;
    o[15] = qs | (max(qe, qs) << 8);
}

__device__ __forceinline__ float4 max4(float4 a, float4 b) {
    float4 r;
    r.x = fmaxf(a.x, b.x); r.y = fmaxf(a.y, b.y);
    r.z = fmaxf(a.z, b.z); r.w = fmaxf(a.w, b.w);
    return r;
}

// One wave = 4 channels of one roi. lane = chsub*16 + cq; quad qabs = qs + cq.
// Per-phase mini-epilogue: after each ph's column maxes land in LDS, lanes
// 0..27 (4ch x 7pw) reduce and store. LDS = 4.4 KB -> ~32 waves/CU.
// Block = 256 threads = 4 independent waves (no barriers). Grid = R * 32.
__global__ __launch_bounds__(256) void roipool_main(
        const float* __restrict__ features,
        const int* __restrict__ wsbuf,
        float* __restrict__ out) {
    __shared__ float cm[4][4][68];   // [wave][chsub][cols] = 4352 B

    int r    = blockIdx.x >> 5;      // 32 blocks per roi (16 ch each)
    int cg   = blockIdx.x & 31;
    int wv   = threadIdx.x >> 6;
    int lane = threadIdx.x & 63;
    int chsub = lane >> 4;           // 0..3: channel within wave
    int cq    = lane & 15;           // quad slot
    int c0   = (cg << 4) + (wv << 2);

    const int* B = wsbuf + r * RLEN; // wave-uniform -> scalar loads
    int b   = B[0];
    int qpk = B[15];
    int qs  = qpk & 255;
    int qe  = qpk >> 8;
    int qabs = qs + cq;
    bool qin = qabs < qe;            // lane active for loads/writes

    const float4* f4 = (const float4*)features;
    int base = ((((b << 9) + c0 + chsub) << 10) | qabs);

    // epilogue lane mapping (4 ch * 7 pw = 28 active lanes)
    int ech = (lane * 9363) >> 16;   // lane/7 (valid for lane<49)
    int epw = lane - ech * 7;
    int ews = B[16 + epw];           // per-lane, L1-hot
    int ewe = B[23 + epw];
    bool eact = lane < 28;
    const float* erow = cm[wv][ech & 3];
    size_t obase = ((size_t)(r << 9) + c0) * 49 + ech * 49 + epw;

    #pragma unroll
    for (int ph = 0; ph < PH; ++ph) {
        int hs = B[1 + ph], he = B[8 + ph];   // wave-uniform scalars
        if (qin) {
            float4 acc = make_float4(-FLT_MAX, -FLT_MAX, -FLT_MAX, -FLT_MAX);
            int n = he - hs;
            int idx = base + (hs << 4);
            while (n >= 4) {                  // 4 loads in flight
                float4 v0 = f4[idx];
                float4 v1 = f4[idx + 16];
                float4 v2 = f4[idx + 32];
                float4 v3 = f4[idx + 48];
                acc = max4(acc, max4(max4(v0, v1), max4(v2, v3)));
                idx += 64; n -= 4;
            }
            if (n >= 2) {
                float4 v0 = f4[idx];
                float4 v1 = f4[idx + 16];
                acc = max4(acc, max4(v0, v1));
                idx += 32; n -= 2;
            }
            if (n > 0) acc = max4(acc, f4[idx]);
            *(float4*)&cm[wv][chsub][qabs << 2] = acc;
        }
        // per-phase epilogue; wave-lockstep program order makes this safe
        if (eact) {
            float m = -FLT_MAX;
            int w = ews;
            for (; w + 2 <= ewe; w += 2)
                m = fmaxf(fmaxf(m, erow[w]), erow[w + 1]);
            if (w < ewe) m = fmaxf(m, erow[w]);
            bool empty = (he <= hs) || (ewe <= ews);
            out[obase + ph * 7] = empty ? 0.0f : m;
        }
    }
}

extern "C" void kernel_launch(void* const* d_in, const int* in_sizes, int n_in,
                              void* d_out, int out_size, void* d_ws, size_t ws_size,
                              hipStream_t stream) {
    const float* features = (const float*)d_in[0];
    const float* rois     = (const float*)d_in[1];
    float* out = (float*)d_out;
    int* wsbuf = (int*)d_ws;

    int R = in_sizes[1] / 5;   // 2000

    roi_bounds_kernel<<<(R + 255) / 256, 256, 0, stream>>>(rois, wsbuf, R);
    roipool_main<<<R * 32, 256, 0, stream>>>(features, wsbuf, out);
}

// Round 12
// 258.322 us; speedup vs baseline: 1.1465x; 1.1465x over previous
//
#include <hip/hip_runtime.h>
#include <math.h>
#include <float.h>

#define PH 7
#define RLEN 32   // ints per roi in workspace

// ---- exact integer emulation of the reference's fast-math f32 binning ----
// bin = RN_f32(roi * RN_f32(1/7));  RN_f32(1/7) = 9586981 * 2^-26
#define C7 9586981LL

__device__ __forceinline__ long long round24(long long v) {
    if (v == 0) return 0;
    int L = 64 - __clzll((unsigned long long)v);
    int sh = L - 24;
    if (sh <= 0) return v;
    long long rem  = v & ((1LL << sh) - 1);
    long long base = v >> sh;
    long long half = 1LL << (sh - 1);
    if (rem > half || (rem == half && (base & 1))) base++;
    return base << sh;
}
__device__ __forceinline__ long long bin_q26(int roi) {
    return round24((long long)roi * C7);
}
__device__ __forceinline__ int floor_k(long long b26, int k) {
    long long v = round24((long long)k * b26);
    return (int)(v >> 26);
}
__device__ __forceinline__ int ceil_k(long long b26, int k) {
    long long v = round24((long long)k * b26);
    return (int)((v + ((1LL << 26) - 1)) >> 26);
}

// Per-ROI bounds (ints): [0]=b, [1..7]=hstart, [8..14]=hend,
// [15] = qs | qe<<8 (window column-quad range), [16..22]=ws, [23..29]=we
__global__ void roi_bounds_kernel(const float* __restrict__ rois,
                                  int* __restrict__ wsbuf, int R) {
    int r = blockIdx.x * blockDim.x + threadIdx.x;
    if (r >= R) return;
    const int H = 64, W = 64;
    const float* roi = rois + r * 5;
    int b  = (int)roi[0];
    int x1 = (int)rintf(roi[1] * 0.0625f);
    int y1 = (int)rintf(roi[2] * 0.0625f);
    int x2 = (int)rintf(roi[3] * 0.0625f);
    int y2 = (int)rintf(roi[4] * 0.0625f);

    int roi_w = max(x2 - x1 + 1, 1);
    int roi_h = max(y2 - y1 + 1, 1);
    long long bh = bin_q26(roi_h);
    long long bw = bin_q26(roi_w);

    int* o = wsbuf + r * RLEN;
    o[0] = b;
    int ws0 = 64, we6 = 0;
    #pragma unroll
    for (int i = 0; i < PH; ++i) {
        int hs = min(max(y1 + floor_k(bh, i),     0), H);
        int he = min(max(y1 + ceil_k (bh, i + 1), 0), H);
        int wst = min(max(x1 + floor_k(bw, i),     0), W);
        int wen = min(max(x1 + ceil_k (bw, i + 1), 0), W);
        o[1 + i]  = hs;
        o[8 + i]  = he;
        o[16 + i] = wst;
        o[23 + i] = wen;
        if (i == 0) ws0 = wst;
        if (i == 6) we6 = wen;
    }
    int qs = ws0 >> 2;
    int qe = (we6 + 3) >> 2;
    o[15] = qs | (max(qe, qs) << 8);
}

__device__ __forceinline__ float4 max4(float4 a, float4 b) {
    float4 r;
    r.x = fmaxf(a.x, b.x); r.y = fmaxf(a.y, b.y);
    r.z = fmaxf(a.z, b.z); r.w = fmaxf(a.w, b.w);
    return r;
}

// One wave = 4 channels of one roi. lane = chsub*16 + cq; quad qabs = qs + cq.
// Per-phase reduce into REGISTERS (vals[7]); one coalesced write pass at end
// staged through the same small LDS slice. LDS = 4.6 KB -> ~32 waves/CU.
// Block = 256 threads = 4 independent waves (no barriers). Grid = R * 32.
__global__ __launch_bounds__(256) void roipool_main(
        const float* __restrict__ features,
        const int* __restrict__ wsbuf,
        float* __restrict__ out) {
    __shared__ float cm[4][4][72];   // [wave][chsub][cols] = 4608 B

    int r    = blockIdx.x >> 5;      // 32 blocks per roi (16 ch each)
    int cg   = blockIdx.x & 31;
    int wv   = threadIdx.x >> 6;
    int lane = threadIdx.x & 63;
    int chsub = lane >> 4;           // 0..3: channel within wave
    int cq    = lane & 15;           // quad slot
    int c0   = (cg << 4) + (wv << 2);

    const int* B = wsbuf + r * RLEN; // wave-uniform -> scalar loads
    int b   = B[0];
    int qpk = B[15];
    int qs  = qpk & 255;
    int qe  = qpk >> 8;
    int qabs = qs + cq;
    bool qin = qabs < qe;            // lane active for loads/writes

    const float4* f4 = (const float4*)features;
    int base = ((((b << 9) + c0 + chsub) << 10) | qabs);

    // epilogue lane mapping (4 ch * 7 pw = 28 active lanes)
    int ech = (lane * 9363) >> 16;   // lane/7 (valid for lane<49)
    int epw = lane - ech * 7;
    int ews = B[16 + epw];           // per-lane, L1-hot
    int ewe = B[23 + epw];
    bool eact = lane < 28;
    const float* erow = cm[wv][ech & 3];
    float vals[PH];

    #pragma unroll
    for (int ph = 0; ph < PH; ++ph) {
        int hs = B[1 + ph], he = B[8 + ph];   // wave-uniform scalars
        if (qin) {
            float4 acc = make_float4(-FLT_MAX, -FLT_MAX, -FLT_MAX, -FLT_MAX);
            int n = he - hs;
            int idx = base + (hs << 4);
            while (n >= 4) {                  // 4 loads in flight
                float4 v0 = f4[idx];
                float4 v1 = f4[idx + 16];
                float4 v2 = f4[idx + 32];
                float4 v3 = f4[idx + 48];
                acc = max4(acc, max4(max4(v0, v1), max4(v2, v3)));
                idx += 64; n -= 4;
            }
            if (n >= 2) {
                float4 v0 = f4[idx];
                float4 v1 = f4[idx + 16];
                acc = max4(acc, max4(v0, v1));
                idx += 32; n -= 2;
            }
            if (n > 0) acc = max4(acc, f4[idx]);
            *(float4*)&cm[wv][chsub][qabs << 2] = acc;
        }
        // per-phase reduce into registers; wave-lockstep order makes this safe
        float m = -FLT_MAX;
        int w = ews;
        for (; w + 2 <= ewe; w += 2)
            m = fmaxf(fmaxf(m, erow[w]), erow[w + 1]);
        if (w < ewe) m = fmaxf(m, erow[w]);
        bool empty = (he <= hs) || (ewe <= ews);
        vals[ph] = empty ? 0.0f : m;
    }

    // stage the wave's 196 outputs (k = ech*49 + ph*7 + epw) then write
    // coalesced; cm[wv] reuse is safe after the last reduce (wave-sync).
    float* stage = (float*)cm[wv];
    if (eact) {
        #pragma unroll
        for (int ph = 0; ph < PH; ++ph)
            stage[ech * 49 + ph * 7 + epw] = vals[ph];
    }
    size_t obase = ((size_t)(r << 9) + c0) * 49;
    #pragma unroll
    for (int it = 0; it < 4; ++it) {
        int f = (it << 6) + lane;
        if (f < 196) out[obase + f] = stage[f];
    }
}

extern "C" void kernel_launch(void* const* d_in, const int* in_sizes, int n_in,
                              void* d_out, int out_size, void* d_ws, size_t ws_size,
                              hipStream_t stream) {
    const float* features = (const float*)d_in[0];
    const float* rois     = (const float*)d_in[1];
    float* out = (float*)d_out;
    int* wsbuf = (int*)d_ws;

    int R = in_sizes[1] / 5;   // 2000

    roi_bounds_kernel<<<(R + 255) / 256, 256, 0, stream>>>(rois, wsbuf, R);
    roipool_main<<<R * 32, 256, 0, stream>>>(features, wsbuf, out);
}

// Round 13
// 232.293 us; speedup vs baseline: 1.2750x; 1.1121x over previous
//
#include <hip/hip_runtime.h>
#include <math.h>
#include <float.h>

#define PH 7
#define RLEN 32   // ints per roi in workspace

// ---- exact integer emulation of the reference's fast-math f32 binning ----
// bin = RN_f32(roi * RN_f32(1/7));  RN_f32(1/7) = 9586981 * 2^-26
#define C7 9586981LL

__device__ __forceinline__ long long round24(long long v) {
    if (v == 0) return 0;
    int L = 64 - __clzll((unsigned long long)v);
    int sh = L - 24;
    if (sh <= 0) return v;
    long long rem  = v & ((1LL << sh) - 1);
    long long base = v >> sh;
    long long half = 1LL << (sh - 1);
    if (rem > half || (rem == half && (base & 1))) base++;
    return base << sh;
}
__device__ __forceinline__ long long bin_q26(int roi) {
    return round24((long long)roi * C7);
}
__device__ __forceinline__ int floor_k(long long b26, int k) {
    long long v = round24((long long)k * b26);
    return (int)(v >> 26);
}
__device__ __forceinline__ int ceil_k(long long b26, int k) {
    long long v = round24((long long)k * b26);
    return (int)((v + ((1LL << 26) - 1)) >> 26);
}

// Per-ROI bounds (ints): [0]=b, [1..7]=hstart, [8..14]=hend,
// [15] = qs | qe<<8 (window column-quad range), [16..22]=ws, [23..29]=we
__global__ void roi_bounds_kernel(const float* __restrict__ rois,
                                  int* __restrict__ wsbuf, int R) {
    int r = blockIdx.x * blockDim.x + threadIdx.x;
    if (r >= R) return;
    const int H = 64, W = 64;
    const float* roi = rois + r * 5;
    int b  = (int)roi[0];
    int x1 = (int)rintf(roi[1] * 0.0625f);
    int y1 = (int)rintf(roi[2] * 0.0625f);
    int x2 = (int)rintf(roi[3] * 0.0625f);
    int y2 = (int)rintf(roi[4] * 0.0625f);

    int roi_w = max(x2 - x1 + 1, 1);
    int roi_h = max(y2 - y1 + 1, 1);
    long long bh = bin_q26(roi_h);
    long long bw = bin_q26(roi_w);

    int* o = wsbuf + r * RLEN;
    o[0] = b;
    int ws0 = 64, we6 = 0;
    #pragma unroll
    for (int i = 0; i < PH; ++i) {
        int hs = min(max(y1 + floor_k(bh, i),     0), H);
        int he = min(max(y1 + ceil_k (bh, i + 1), 0), H);
        int wst = min(max(x1 + floor_k(bw, i),     0), W);
        int wen = min(max(x1 + ceil_k (bw, i + 1), 0), W);
        o[1 + i]  = hs;
        o[8 + i]  = he;
        o[16 + i] = wst;
        o[23 + i] = wen;
        if (i == 0) ws0 = wst;
        if (i == 6) we6 = wen;
    }
    int qs = ws0 >> 2;
    int qe = (we6 + 3) >> 2;
    o[15] = qs | (max(qe, qs) << 8);
}

__device__ __forceinline__ float4 max4(float4 a, float4 b) {
    float4 r;
    r.x = fmaxf(a.x, b.x); r.y = fmaxf(a.y, b.y);
    r.z = fmaxf(a.z, b.z); r.w = fmaxf(a.w, b.w);
    return r;
}

// One wave = 8 channels of one roi. lane = chsub*8 + cq8; quad = qs+tile*8+cq8.
// 1 tile pass covers windows <=32 cols (~73% of ROIs), else 2 passes.
// Per-phase reduce into registers (vals[7]); one coalesced 392-float write at
// the end, staged through the wave's own LDS slice. No barriers.
// Block = 256 threads = 4 independent waves. Grid = R * 16.
__global__ __launch_bounds__(256) void roipool_main(
        const float* __restrict__ features,
        const int* __restrict__ wsbuf,
        float* __restrict__ out) {
    __shared__ float cm[4][8][68];   // [wave][chsub][cols] = 8704 B

    int r    = blockIdx.x >> 4;      // 16 blocks per roi (32 ch each)
    int cg   = blockIdx.x & 15;
    int wv   = threadIdx.x >> 6;
    int lane = threadIdx.x & 63;
    int chsub = lane >> 3;           // 0..7: channel within wave
    int cq8   = lane & 7;            // quad slot within tile
    int c0   = (cg << 5) + (wv << 3);

    const int* B = wsbuf + r * RLEN; // wave-uniform -> scalar loads
    int b   = B[0];
    int qpk = B[15];
    int qs  = qpk & 255;
    int qe  = qpk >> 8;
    int ntiles = (qe - qs + 7) >> 3; // 0..2

    const float4* f4 = (const float4*)features;
    int cbase = ((b << 9) + c0 + chsub) << 10;

    // epilogue lane mapping (8 ch * 7 pw = 56 active lanes)
    int ech = (lane * 9363) >> 16;   // lane/7 for lane<56
    int epw = lane - ech * 7;
    int ews = B[16 + epw];           // per-lane, L1-hot
    int ewe = B[23 + epw];
    bool eact = lane < 56;
    const float* erow = cm[wv][ech & 7];
    float vals[PH];

    #pragma unroll
    for (int ph = 0; ph < PH; ++ph) {
        int hs = B[1 + ph], he = B[8 + ph];   // wave-uniform scalars
        for (int t = 0; t < ntiles; ++t) {
            int qabs = qs + (t << 3) + cq8;
            if (qabs < qe) {
                float4 acc = make_float4(-FLT_MAX, -FLT_MAX, -FLT_MAX, -FLT_MAX);
                int n = he - hs;
                int idx = cbase + (hs << 4) + qabs;
                while (n >= 4) {                  // 4 loads in flight
                    float4 v0 = f4[idx];
                    float4 v1 = f4[idx + 16];
                    float4 v2 = f4[idx + 32];
                    float4 v3 = f4[idx + 48];
                    acc = max4(acc, max4(max4(v0, v1), max4(v2, v3)));
                    idx += 64; n -= 4;
                }
                if (n >= 2) {
                    float4 v0 = f4[idx];
                    float4 v1 = f4[idx + 16];
                    acc = max4(acc, max4(v0, v1));
                    idx += 32; n -= 2;
                }
                if (n > 0) acc = max4(acc, f4[idx]);
                *(float4*)&cm[wv][chsub][qabs << 2] = acc;
            }
        }
        // per-phase reduce into registers; wave-lockstep order makes this safe
        float m = -FLT_MAX;
        int w = ews;
        for (; w + 2 <= ewe; w += 2)
            m = fmaxf(fmaxf(m, erow[w]), erow[w + 1]);
        if (w < ewe) m = fmaxf(m, erow[w]);
        bool empty = (he <= hs) || (ewe <= ews);
        vals[ph] = empty ? 0.0f : m;
    }

    // stage the wave's 392 outputs (k = ech*49 + ph*7 + epw) then write
    // coalesced; cm[wv] reuse is safe after the last reduce (wave-sync).
    float* stage = (float*)cm[wv];
    if (eact) {
        #pragma unroll
        for (int ph = 0; ph < PH; ++ph)
            stage[ech * 49 + ph * 7 + epw] = vals[ph];
    }
    size_t obase = ((size_t)(r << 9) + c0) * 49;
    #pragma unroll
    for (int it = 0; it < 7; ++it) {
        int f = (it << 6) + lane;
        if (f < 392) out[obase + f] = stage[f];
    }
}

extern "C" void kernel_launch(void* const* d_in, const int* in_sizes, int n_in,
                              void* d_out, int out_size, void* d_ws, size_t ws_size,
                              hipStream_t stream) {
    const float* features = (const float*)d_in[0];
    const float* rois     = (const float*)d_in[1];
    float* out = (float*)d_out;
    int* wsbuf = (int*)d_ws;

    int R = in_sizes[1] / 5;   // 2000

    roi_bounds_kernel<<<(R + 255) / 256, 256, 0, stream>>>(rois, wsbuf, R);
    roipool_main<<<R * 16, 256, 0, stream>>>(features, wsbuf, out);
}